// Round 5
// baseline (523.780 us; speedup 1.0000x reference)
//
#include <hip/hip_runtime.h>
#include <stdint.h>

// Periodic radius-graph neighbor list (AlphaNet). B=16, N=256, C=27, M=6912.
// Outputs (flat f32 concat): dist [B,N,M], dvec [B,N,M,3], num_neighbors_image [B].
// keep = (1e-4 < dsqr <= 25) AND stable-sort rank < 32
//      == key (f32bits(dsqr)<<32 | m) among the 32 smallest within-radius keys.
//
// R5: memset (rocclr fill path, 6.2 TB/s) + edges kernel + scatter kernel,
// with DETERMINISTIC per-receiver edge slots (eidx[bi*32+rank]) — no contended
// global atomics (R3's single-counter append cost ~+80 us of L2 serialization).

constexpr int B_ = 16, N_ = 256, C_ = 27;
constexpr int M_ = N_ * C_;        // 6912
constexpr int MAXC = 256;          // LDS candidate slots; mean ~78
constexpr int KMAX = 32;
constexpr int NR   = B_ * N_;      // 4096 receivers

__global__ __launch_bounds__(256)
void edges_kernel(const float* __restrict__ pos,    // [B,N,3]
                  const float* __restrict__ cell,   // [B,3,3]
                  float* __restrict__ nn,           // [B] float counts (pre-zeroed)
                  int*   __restrict__ ecnt,         // [NR] kept-edge count
                  int*   __restrict__ eidx,         // [NR*KMAX] m per (receiver,rank)
                  float4* __restrict__ evals)       // [NR*KMAX] dx,dy,dz,dsq
{
#pragma clang fp contract(off)
    __shared__ float offx[C_], offy[C_], offz[C_];
    __shared__ unsigned long long keys[MAXC];
    __shared__ float4 vals[MAXC];
    __shared__ int cnt;

    const int bi  = blockIdx.x;   // b*N + i
    const int b   = bi >> 8;
    const int i   = bi & 255;
    const int tid = threadIdx.x;

    const float* pb = pos + b * N_ * 3;
    // thread owns source atom j = tid; receiver i is wave-uniform (scalar loads)
    const float pjx = pb[tid * 3 + 0], pjy = pb[tid * 3 + 1], pjz = pb[tid * 3 + 2];
    const float pix = pb[i * 3 + 0],   piy = pb[i * 3 + 1],   piz = pb[i * 3 + 2];

    if (tid < C_) {
        const float n1 = (float)(tid / 9 - 1);
        const float n2 = (float)((tid / 3) % 3 - 1);
        const float n3 = (float)(tid % 3 - 1);
        const float* cb = cell + b * 9;
        offx[tid] = n1 * cb[0] + n2 * cb[3] + n3 * cb[6];
        offy[tid] = n1 * cb[1] + n2 * cb[4] + n3 * cb[7];
        offz[tid] = n1 * cb[2] + n2 * cb[5] + n3 * cb[8];
    }
    if (tid == 0) cnt = 0;
    __syncthreads();

    // pass 1: bit-exact numpy order: s = pj + off; d = pi - s; ((dx*dx+dy*dy)+dz*dz)
    #pragma unroll 1
    for (int c = 0; c < C_; ++c) {
        const float sx = pjx + offx[c], sy = pjy + offy[c], sz = pjz + offz[c];
        const float dx = pix - sx, dy = piy - sy, dz = piz - sz;
        const float dsq = dx * dx + dy * dy + dz * dz;
        if (dsq <= 25.0f && dsq > 1e-4f) {
            const int idx = atomicAdd(&cnt, 1);              // LDS atomic only
            if (idx < MAXC) {
                keys[idx] = ((unsigned long long)__float_as_uint(dsq) << 32)
                          | (unsigned)(tid * C_ + c);
                vals[idx] = make_float4(dx, dy, dz, dsq);
            }
        }
    }
    __syncthreads();

    int K = cnt; if (K > MAXC) K = MAXC;
    const int kept = (K < KMAX) ? K : KMAX;
    if (tid == 0) {
        ecnt[bi] = kept;
        atomicAdd(&nn[b], (float)kept);                      // 16 addrs, light
    }

    // rank scan (keys unique -> rank is a perfect compact index < kept)
    for (int idx = tid; idx < K; idx += 256) {
        const unsigned long long key = keys[idx];
        int r = 0;
        for (int q = 0; q < K; ++q) r += (keys[q] < key) ? 1 : 0;
        if (r < KMAX) {
            eidx[bi * KMAX + r]  = (int)(key & 0xffffffffu); // m
            evals[bi * KMAX + r] = vals[idx];
        }
    }
}

__global__ __launch_bounds__(256)
void scatter_kernel(const int* __restrict__ ecnt,
                    const int* __restrict__ eidx,
                    const float4* __restrict__ evals,
                    float* __restrict__ dist,      // [B*N*M] (pre-zeroed)
                    float* __restrict__ dvec)      // [B*N*M*3] (pre-zeroed)
{
    const int e  = blockIdx.x * 256 + threadIdx.x;   // e = bi*32 + r
    const int bi = e >> 5;
    const int r  = e & 31;
    if (r >= ecnt[bi]) return;
    const int m  = eidx[e];
    const float4 v = evals[e];
    const size_t id = (size_t)bi * M_ + (size_t)m;
    dist[id] = sqrtf(v.w);
    dvec[3 * id + 0] = v.x;
    dvec[3 * id + 1] = v.y;
    dvec[3 * id + 2] = v.z;
}

extern "C" void kernel_launch(void* const* d_in, const int* in_sizes, int n_in,
                              void* d_out, int out_size, void* d_ws, size_t ws_size,
                              hipStream_t stream)
{
    const float* pos  = (const float*)d_in[0];
    const float* cell = (const float*)d_in[1];
    float* dist = (float*)d_out;
    float* dvec = dist + (size_t)B_ * N_ * M_;
    float* nn   = dvec + (size_t)B_ * N_ * M_ * 3;

    // ws layout (all 16B-aligned): ecnt[NR] | eidx[NR*KMAX] | evals[NR*KMAX]
    int*    ecnt  = (int*)d_ws;                                   // 16 KB
    int*    eidx  = (int*)((char*)d_ws + (size_t)NR * 4);         // 512 KB
    float4* evals = (float4*)((char*)d_ws + (size_t)NR * 4 + (size_t)NR * KMAX * 4);

    // 1) zero the entire output (dist + dvec + nn) via the 6.2 TB/s fill path
    hipMemsetAsync(d_out, 0, (size_t)out_size * sizeof(float), stream);
    // 2) kept edges into deterministic per-receiver slots (no global atomics)
    edges_kernel<<<dim3(NR), dim3(256), 0, stream>>>(pos, cell, nn, ecnt, eidx, evals);
    // 3) scatter the <=131072 kept edges into the zeroed output
    scatter_kernel<<<dim3(NR * KMAX / 256), dim3(256), 0, stream>>>(ecnt, eidx, evals, dist, dvec);
}